// Round 4
// baseline (338.675 us; speedup 1.0000x reference)
//
#include <hip/hip_runtime.h>
#include <hip/hip_bf16.h>

// Problem constants
#define NQ 8192            // B*S flattened tokens
#define DIM 64             // embed dim
#define SPLITS 16          // key-dimension split (partials merged later)
#define QBLK 128           // queries per block (4 waves x 32)
#define BN 64              // keys per LDS tile
#define KEYS_PER_SPLIT (NQ / SPLITS)       // 512
#define NTILES (KEYS_PER_SPLIT / BN)       // 8
#define GRID_FLASH ((NQ / QBLK) * SPLITS)  // 1024
#define TAILB 256          // blocks that perform the fused merge
#define MROWS 32           // rows merged per tail block (256*32 = 8192)
#define SC2 0.51012301920911057f           // (1/sqrt(8)) * log2(e)

#define KSTR 72            // ksh/wsh row stride in shorts (bank-friendly)
#define VSTR 68            // vsh row stride in shorts

typedef short s8v __attribute__((ext_vector_type(8)));   // 8 x bf16 bits
typedef short s4v __attribute__((ext_vector_type(4)));   // 4 x bf16 bits
typedef float f4v __attribute__((ext_vector_type(4)));
typedef int   i4v __attribute__((ext_vector_type(4)));

__device__ __forceinline__ float b2f(short s) {
  unsigned int u = ((unsigned int)(unsigned short)s) << 16;
  return __uint_as_float(u);
}
__device__ __forceinline__ short f2b(float f) {
  __hip_bfloat16 h = __float2bfloat16(f);
  return *reinterpret_cast<short*>(&h);
}
__device__ __forceinline__ int pack_bf16x2(float a, float b) {
  union { __hip_bfloat162 h; int i; } u;
  u.h = __float22bfloat162_rn(make_float2(a, b));
  return u.i;
}

// ---------------- QKV projection + quantum map (fp32 in, bf16 out) ----------
// q_q[n,e] = cos(theta[e]) * cos( sum_d x[n,d]*W[e,d] + b[e] )
#define QROWS 16
__global__ __launch_bounds__(256) void qkv_kernel(
    const float* __restrict__ x,
    const float* __restrict__ wq, const float* __restrict__ bq,
    const float* __restrict__ wk, const float* __restrict__ bk,
    const float* __restrict__ wv, const float* __restrict__ bv,
    const float* __restrict__ theta,
    short* __restrict__ qq, short* __restrict__ kq, short* __restrict__ vq,
    unsigned int* cnt, int fused) {
  if (fused && blockIdx.x == 0 && threadIdx.x == 0)
    __hip_atomic_store(cnt, 0u, __ATOMIC_RELAXED, __HIP_MEMORY_SCOPE_AGENT);
  __shared__ __align__(16) short wsh[3][DIM][KSTR];  // bf16 weights
  __shared__ __align__(16) short xsb[QROWS][DIM];    // bf16 x rows
  int tid = threadIdx.x;
  for (int i = tid; i < 3 * DIM * 16; i += 256) {
    int m = i >> 10;
    int rem = i & 1023;
    int r = rem >> 4, c4 = (rem & 15) << 2;
    const float* src = (m == 0) ? wq : (m == 1) ? wk : wv;
    float4 w = *(const float4*)&src[r * DIM + c4];
    s4v p = {f2b(w.x), f2b(w.y), f2b(w.z), f2b(w.w)};
    *(s4v*)&wsh[m][r][c4] = p;
  }
  int rowbase = blockIdx.x * QROWS;
  for (int i = tid; i < QROWS * 16; i += 256) {
    int r = i >> 4, c4 = (i & 15) << 2;
    float4 v = *(const float4*)&x[(rowbase + r) * DIM + c4];
    s4v p = {f2b(v.x), f2b(v.y), f2b(v.z), f2b(v.w)};
    *(s4v*)&xsb[r][c4] = p;
  }
  __syncthreads();
  int e = tid & 63, rg = tid >> 6;
  float ct = __cosf(theta[e]);
  float bqv = bq[e], bkv = bk[e], bvv = bv[e];
  for (int r = rg; r < QROWS; r += 4) {
    float aq = bqv, ak = bkv, av = bvv;
#pragma unroll
    for (int c8 = 0; c8 < 8; ++c8) {
      s8v xv = *(const s8v*)&xsb[r][c8 * 8];
      s8v w0 = *(const s8v*)&wsh[0][e][c8 * 8];
      s8v w1 = *(const s8v*)&wsh[1][e][c8 * 8];
      s8v w2 = *(const s8v*)&wsh[2][e][c8 * 8];
#pragma unroll
      for (int j = 0; j < 8; ++j) {
        float xf = b2f(xv[j]);
        aq += xf * b2f(w0[j]);
        ak += xf * b2f(w1[j]);
        av += xf * b2f(w2[j]);
      }
    }
    int n = rowbase + r;
    qq[n * DIM + e] = f2b(ct * __cosf(aq));
    kq[n * DIM + e] = f2b(ct * __cosf(ak));
    vq[n * DIM + e] = f2b(ct * __cosf(av));
  }
}

// ---------------- shared merge body (tail of flash, or fallback kernel) -----
__device__ __forceinline__ void merge_rows(
    int q0, const short* __restrict__ pO, const short* __restrict__ pL,
    const float* __restrict__ wo, const float* __restrict__ bo,
    float* __restrict__ out, short* wsh, float* att) {
  int tid = threadIdx.x;
  for (int i = tid; i < DIM * 16; i += 256) {
    int r = i >> 4, c4 = (i & 15) << 2;
    float4 w = *(const float4*)&wo[r * DIM + c4];
    s4v p = {f2b(w.x), f2b(w.y), f2b(w.z), f2b(w.w)};
    *(s4v*)&wsh[r * KSTR + c4] = p;
  }
  int e = tid & 63, rg = tid >> 6;
  for (int rr = rg; rr < MROWS; rr += 4) {
    int q = q0 + rr;
    float s = 0.f, l = 0.f;
#pragma unroll
    for (int sp = 0; sp < SPLITS; ++sp) {
      s += b2f(pO[((size_t)sp * NQ + q) * DIM + e]);
      l += b2f(pL[sp * NQ + q]);
    }
    att[rr * DIM + e] = s / l;
  }
  __syncthreads();
  for (int rr = rg; rr < MROWS; rr += 4) {
    float acc = bo[e];
#pragma unroll
    for (int c8 = 0; c8 < 8; ++c8) {
      s8v w = *(const s8v*)&wsh[e * KSTR + c8 * 8];
      const float* ar = &att[rr * DIM + c8 * 8];
      acc += ar[0] * b2f(w[0]) + ar[1] * b2f(w[1]) + ar[2] * b2f(w[2]) + ar[3] * b2f(w[3])
           + ar[4] * b2f(w[4]) + ar[5] * b2f(w[5]) + ar[6] * b2f(w[6]) + ar[7] * b2f(w[7]);
    }
    out[(size_t)(q0 + rr) * DIM + e] = acc;
  }
}

// ---------------- Flash attention (no-max streaming softmax) ----------------
// |s| <= 64/sqrt(8) = 22.6 -> exp(s) <= 6.6e9, row sums <= 5.5e13: fp32-safe,
// so no running max; split partials merge by pure summation.
// QK computed as S^T (A=K, B=Q): exp'd C-regs are directly a PV A-operand.
// PV uses K=32 MFMA: pa = concat(kt0-regs, kt1-regs) gives key order
// quad*4+(j&3)+16*(j>>2); the V B-frag is read with the SAME permutation.
__global__ __launch_bounds__(256, 4) void flash_kernel(
    const short* __restrict__ qq, const short* __restrict__ kq,
    const short* __restrict__ vq,
    short* __restrict__ pO, short* __restrict__ pL,
    unsigned int* cnt,
    const float* __restrict__ wo, const float* __restrict__ bo,
    float* __restrict__ out, int fused) {
  __shared__ __align__(16) short ksh[BN * KSTR];   // [key][dim]; tail: wo tile
  __shared__ __align__(16) short vsh[DIM * VSTR];  // [dim][key]; tail: att
  __shared__ unsigned int tkt_s;

  int tid = threadIdx.x;
  int wave = tid >> 6, lane = tid & 63;
  int l15 = lane & 15, quad = lane >> 4;
  int qblock = blockIdx.x >> 4, split = blockIdx.x & 15;
  int qbase = qblock * QBLK + wave * 32;

  // Q B-frags: B[n=query=l15][k=dim=quad*8+j], two k-halves
  s8v qf[2][2];
#pragma unroll
  for (int qt = 0; qt < 2; ++qt) {
    const short* qr = qq + (qbase + qt * 16 + l15) * DIM + quad * 8;
    qf[qt][0] = *(const s8v*)qr;
    qf[qt][1] = *(const s8v*)(qr + 32);
  }

  f4v o[2][4];
  float ls[2] = {0.f, 0.f};
#pragma unroll
  for (int qt = 0; qt < 2; ++qt)
#pragma unroll
    for (int c = 0; c < 4; ++c) o[qt][c] = (f4v){0.f, 0.f, 0.f, 0.f};

  int vkp = tid & 31, vdc = tid >> 5;   // V-transpose staging coords

  int kstart = split * KEYS_PER_SPLIT;
  for (int t = 0; t < NTILES; ++t) {
    int kbase = kstart + t * BN;
    __syncthreads();  // (A) previous tile's LDS fully consumed
    // stage K rows (b128 writes, stride-72 rows)
    for (int i = tid; i < 512; i += 256) {
      int key = i >> 3, c8 = (i & 7) << 3;
      *(s8v*)&ksh[key * KSTR + c8] = *(const s8v*)&kq[(kbase + key) * DIM + c8];
    }
    // stage V transposed [dim][key]: 2 key rows -> packed key-pair b32 writes
    {
      s8v r0 = *(const s8v*)&vq[(kbase + 2 * vkp) * DIM + (vdc << 3)];
      s8v r1 = *(const s8v*)&vq[(kbase + 2 * vkp + 1) * DIM + (vdc << 3)];
#pragma unroll
      for (int j = 0; j < 8; ++j) {
        int d = (vdc << 3) + j;
        int pk = (int)(unsigned short)r0[j] | ((int)(unsigned short)r1[j] << 16);
        *(int*)&vsh[d * VSTR + 2 * vkp] = pk;
      }
    }
    __syncthreads();  // (B) staging visible

#pragma unroll
    for (int kp = 0; kp < 2; ++kp) {   // pair of 16-key sub-tiles
      i4v pai[2];                      // exp'd P, A-operand bits, per qt
#pragma unroll
      for (int h = 0; h < 2; ++h) {
        int kt = kp * 2 + h;
        const short* kr = &ksh[(kt * 16 + l15) * KSTR + quad * 8];
        s8v kf0 = *(const s8v*)kr;
        s8v kf1 = *(const s8v*)(kr + 32);
#pragma unroll
        for (int qt = 0; qt < 2; ++qt) {
          f4v acc = (f4v){0.f, 0.f, 0.f, 0.f};
          acc = __builtin_amdgcn_mfma_f32_16x16x32_bf16(kf0, qf[qt][0], acc, 0, 0, 0);
          acc = __builtin_amdgcn_mfma_f32_16x16x32_bf16(kf1, qf[qt][1], acc, 0, 0, 0);
          // acc[r] = S^T[key=kt*16+quad*4+r][query=qt*16+l15]
          float p0 = exp2f(acc[0] * SC2), p1 = exp2f(acc[1] * SC2);
          float p2 = exp2f(acc[2] * SC2), p3 = exp2f(acc[3] * SC2);
          ls[qt] += (p0 + p1) + (p2 + p3);
          pai[qt][h * 2]     = pack_bf16x2(p0, p1);
          pai[qt][h * 2 + 1] = pack_bf16x2(p2, p3);
        }
      }
#pragma unroll
      for (int c = 0; c < 4; ++c) {
        // B[n=dim=l15][k=quad*8+j] with key = kp*32 + quad*4+(j&3)+16*(j>>2)
        const short* vr = &vsh[(c * 16 + l15) * VSTR + kp * 32 + quad * 4];
        s4v v0 = *(const s4v*)vr;
        s4v v1 = *(const s4v*)(vr + 16);
        s8v vf = __builtin_shufflevector(v0, v1, 0, 1, 2, 3, 4, 5, 6, 7);
#pragma unroll
        for (int qt = 0; qt < 2; ++qt)
          o[qt][c] = __builtin_amdgcn_mfma_f32_16x16x32_bf16(
              __builtin_bit_cast(s8v, pai[qt]), vf, o[qt][c], 0, 0, 0);
      }
    }
  }

  // finish per-query row sums across quads (lane bits 4,5)
#pragma unroll
  for (int qt = 0; qt < 2; ++qt) {
    float v = ls[qt];
    v += __shfl_xor(v, 16);
    v += __shfl_xor(v, 32);
    ls[qt] = v;
  }

  // store bf16 partials + row sums
#pragma unroll
  for (int qt = 0; qt < 2; ++qt) {
#pragma unroll
    for (int r = 0; r < 4; ++r) {
      int q = qbase + qt * 16 + quad * 4 + r;
      size_t ob = ((size_t)split * NQ + q) * DIM;
#pragma unroll
      for (int c = 0; c < 4; ++c)
        pO[ob + c * 16 + l15] = f2b(o[qt][c][r]);
    }
    if (quad == 0) pL[split * NQ + qbase + qt * 16 + l15] = f2b(ls[qt]);
  }

  if (!fused) return;

  // ------- fused merge tail: last TAILB finisher blocks do the projection ---
  __threadfence();          // make this thread's pO/pL writes device-visible
  __syncthreads();
  if (tid == 0)
    tkt_s = __hip_atomic_fetch_add(cnt, 1u, __ATOMIC_ACQ_REL,
                                   __HIP_MEMORY_SCOPE_AGENT);
  __syncthreads();
  unsigned tkt = tkt_s;
  if (tkt < GRID_FLASH - TAILB) return;
  if (tid == 0) {
    while (__hip_atomic_load(cnt, __ATOMIC_ACQUIRE, __HIP_MEMORY_SCOPE_AGENT)
           < GRID_FLASH)
      __builtin_amdgcn_s_sleep(2);
  }
  __syncthreads();
  __threadfence();          // acquire: all producers' writes now visible
  merge_rows((int)(tkt - (GRID_FLASH - TAILB)) * MROWS, pO, pL, wo, bo, out,
             ksh, (float*)vsh);
}

// ---------------- fallback merge kernel (if ws lacks room for the counter) --
__global__ __launch_bounds__(256) void merge_kernel(
    const short* __restrict__ pO, const short* __restrict__ pL,
    const float* __restrict__ wo, const float* __restrict__ bo,
    float* __restrict__ out) {
  __shared__ __align__(16) short wsh[DIM * KSTR];
  __shared__ __align__(16) float att[MROWS * DIM];
  merge_rows(blockIdx.x * MROWS, pO, pL, wo, bo, out, wsh, att);
}

extern "C" void kernel_launch(void* const* d_in, const int* in_sizes, int n_in,
                              void* d_out, int out_size, void* d_ws, size_t ws_size,
                              hipStream_t stream) {
  const float* x  = (const float*)d_in[0];
  const float* wq = (const float*)d_in[1];
  const float* bq = (const float*)d_in[2];
  const float* wk = (const float*)d_in[3];
  const float* bk = (const float*)d_in[4];
  const float* wv = (const float*)d_in[5];
  const float* bv = (const float*)d_in[6];
  const float* th = (const float*)d_in[7];
  const float* wo = (const float*)d_in[8];
  const float* bo = (const float*)d_in[9];

  char* ws = (char*)d_ws;
  short* qq = (short*)(ws);                             // 1 MB
  short* kq = (short*)(ws + (1u << 20));                // 1 MB
  short* vq = (short*)(ws + (2u << 20));                // 1 MB
  short* pO = (short*)(ws + (3u << 20));                // 16 MB bf16 partials
  short* pL = (short*)(ws + (19u << 20));               // 256 KB bf16 row sums
  unsigned int* cnt = (unsigned int*)(ws + (19u << 20) + (256u << 10));
  int fused = ws_size >= ((19u << 20) + (256u << 10) + 4u);

  hipLaunchKernelGGL(qkv_kernel, dim3(NQ / QROWS), dim3(256), 0, stream,
                     x, wq, bq, wk, bk, wv, bv, th, qq, kq, vq, cnt, fused);
  hipLaunchKernelGGL(flash_kernel, dim3(GRID_FLASH), dim3(256), 0, stream,
                     qq, kq, vq, pO, pL, cnt, wo, bo, (float*)d_out, fused);
  if (!fused)
    hipLaunchKernelGGL(merge_kernel, dim3(NQ / MROWS), dim3(256), 0, stream,
                       pO, pL, wo, bo, (float*)d_out);
}

// Round 5
// 143.424 us; speedup vs baseline: 2.3614x; 2.3614x over previous
//
#include <hip/hip_runtime.h>
#include <hip/hip_bf16.h>

// Problem constants
#define NQ 8192            // B*S flattened tokens
#define DIM 64             // embed dim
#define SPLITS 16          // key-dimension split (partials merged by kernel 3)
#define QBLK 128           // queries per block (4 waves x 32)
#define BN 64              // keys per LDS tile
#define KEYS_PER_SPLIT (NQ / SPLITS)       // 512
#define NTILES (KEYS_PER_SPLIT / BN)       // 8
#define GRID_FLASH ((NQ / QBLK) * SPLITS)  // 1024
#define MERGEB 256         // merge grid
#define MROWS (NQ / MERGEB)                // 32 rows per merge block
#define SC2 0.51012301920911057f           // (1/sqrt(8)) * log2(e)

#define KSTR 72            // wo LDS row stride in shorts (bank-friendly)
#define VSTR 68            // vsh row stride in shorts

typedef short s8v __attribute__((ext_vector_type(8)));   // 8 x bf16 bits
typedef short s4v __attribute__((ext_vector_type(4)));   // 4 x bf16 bits
typedef float f4v __attribute__((ext_vector_type(4)));
typedef int   i4v __attribute__((ext_vector_type(4)));

__device__ __forceinline__ float b2f(short s) {
  unsigned int u = ((unsigned int)(unsigned short)s) << 16;
  return __uint_as_float(u);
}
__device__ __forceinline__ short f2b(float f) {
  __hip_bfloat16 h = __float2bfloat16(f);
  return *reinterpret_cast<short*>(&h);
}
__device__ __forceinline__ int pack_bf16x2(float a, float b) {
  union { __hip_bfloat162 h; int i; } u;
  u.h = __float22bfloat162_rn(make_float2(a, b));
  return u.i;
}

// ---------------- QKV projection + quantum map (fp32 in, bf16 out) ----------
// q_q[n,e] = cos(theta[e]) * cos( sum_d x[n,d]*W[e,d] + b[e] )
#define QROWS 16
__global__ __launch_bounds__(256) void qkv_kernel(
    const float* __restrict__ x,
    const float* __restrict__ wq, const float* __restrict__ bq,
    const float* __restrict__ wk, const float* __restrict__ bk,
    const float* __restrict__ wv, const float* __restrict__ bv,
    const float* __restrict__ theta,
    short* __restrict__ qq, short* __restrict__ kq, short* __restrict__ vq) {
  __shared__ __align__(16) short wsh[3][DIM][KSTR];  // bf16 weights
  __shared__ __align__(16) short xsb[QROWS][DIM];    // bf16 x rows
  int tid = threadIdx.x;
  for (int i = tid; i < 3 * DIM * 16; i += 256) {
    int m = i >> 10;
    int rem = i & 1023;
    int r = rem >> 4, c4 = (rem & 15) << 2;
    const float* src = (m == 0) ? wq : (m == 1) ? wk : wv;
    float4 w = *(const float4*)&src[r * DIM + c4];
    s4v p = {f2b(w.x), f2b(w.y), f2b(w.z), f2b(w.w)};
    *(s4v*)&wsh[m][r][c4] = p;
  }
  int rowbase = blockIdx.x * QROWS;
  for (int i = tid; i < QROWS * 16; i += 256) {
    int r = i >> 4, c4 = (i & 15) << 2;
    float4 v = *(const float4*)&x[(rowbase + r) * DIM + c4];
    s4v p = {f2b(v.x), f2b(v.y), f2b(v.z), f2b(v.w)};
    *(s4v*)&xsb[r][c4] = p;
  }
  __syncthreads();
  int e = tid & 63, rg = tid >> 6;
  float ct = __cosf(theta[e]);
  float bqv = bq[e], bkv = bk[e], bvv = bv[e];
  for (int r = rg; r < QROWS; r += 4) {
    float aq = bqv, ak = bkv, av = bvv;
#pragma unroll
    for (int c8 = 0; c8 < 8; ++c8) {
      s8v xv = *(const s8v*)&xsb[r][c8 * 8];
      s8v w0 = *(const s8v*)&wsh[0][e][c8 * 8];
      s8v w1 = *(const s8v*)&wsh[1][e][c8 * 8];
      s8v w2 = *(const s8v*)&wsh[2][e][c8 * 8];
#pragma unroll
      for (int j = 0; j < 8; ++j) {
        float xf = b2f(xv[j]);
        aq += xf * b2f(w0[j]);
        ak += xf * b2f(w1[j]);
        av += xf * b2f(w2[j]);
      }
    }
    int n = rowbase + r;
    qq[n * DIM + e] = f2b(ct * __cosf(aq));
    kq[n * DIM + e] = f2b(ct * __cosf(ak));
    vq[n * DIM + e] = f2b(ct * __cosf(av));
  }
}

// ---------------- Flash attention (no-max streaming softmax) ----------------
// |s| <= 64/sqrt(8) = 22.6 -> exp(s) <= 6.6e9, row sums <= 5.5e13: fp32-safe,
// so no running max; split partials merge by pure summation.
// QK computed as S^T (A=K, B=Q): exp'd C-regs are directly a PV A-operand.
// PV uses K=32 MFMA: pai = concat(kt0-regs, kt1-regs) gives key order
// kp*32 + quad*4+(j&3)+16*(j>>2); the V B-frag is read with the SAME perm.
// K fragments come straight from global (L1/L2-hit, aligned dwordx4) -- only
// V needs an LDS transpose, double-buffered with ONE barrier per tile.
__global__ __launch_bounds__(256, 4) void flash_kernel(
    const short* __restrict__ qq, const short* __restrict__ kq,
    const short* __restrict__ vq,
    short* __restrict__ pO, short* __restrict__ pL) {
  __shared__ __align__(16) short vsh[2][DIM * VSTR];  // [dim][key] transposed

  int tid = threadIdx.x;
  int wave = tid >> 6, lane = tid & 63;
  int l15 = lane & 15, quad = lane >> 4;
  int qblock = blockIdx.x >> 4, split = blockIdx.x & 15;
  int qbase = qblock * QBLK + wave * 32;

  // Q B-frags: B[n=query=l15][k=dim=quad*8+j], two k-halves
  s8v qf[2][2];
#pragma unroll
  for (int qt = 0; qt < 2; ++qt) {
    const short* qr = qq + (qbase + qt * 16 + l15) * DIM + quad * 8;
    qf[qt][0] = *(const s8v*)qr;
    qf[qt][1] = *(const s8v*)(qr + 32);
  }

  f4v o[2][4];
  float ls[2] = {0.f, 0.f};
#pragma unroll
  for (int qt = 0; qt < 2; ++qt)
#pragma unroll
    for (int c = 0; c < 4; ++c) o[qt][c] = (f4v){0.f, 0.f, 0.f, 0.f};

  int vkp = tid & 31, vdc = tid >> 5;   // V-transpose staging coords
  int kstart = split * KEYS_PER_SPLIT;

  // stage V tile t into buffer buf: [dim][key], packed key-pair b32 writes
#define STAGE_V(t, buf)                                                      \
  {                                                                          \
    int kb_ = kstart + (t) * BN;                                             \
    s8v r0 = *(const s8v*)&vq[(kb_ + 2 * vkp) * DIM + (vdc << 3)];           \
    s8v r1 = *(const s8v*)&vq[(kb_ + 2 * vkp + 1) * DIM + (vdc << 3)];       \
    _Pragma("unroll") for (int j = 0; j < 8; ++j) {                          \
      int d = (vdc << 3) + j;                                                \
      int pk = (int)(unsigned short)r0[j] | ((int)(unsigned short)r1[j] << 16); \
      *(int*)&vsh[buf][d * VSTR + 2 * vkp] = pk;                             \
    }                                                                        \
  }

  STAGE_V(0, 0)

  for (int t = 0; t < NTILES; ++t) {
    __syncthreads();  // staging of buf t&1 visible; buf (t+1)&1 free to write
    if (t + 1 < NTILES) STAGE_V(t + 1, (t + 1) & 1)

    int kbase = kstart + t * BN;
    // K A-frags straight from global: A[m=key=l15][k=dim=quad*8+j]
    s8v kf[4][2];
#pragma unroll
    for (int kt = 0; kt < 4; ++kt) {
      const short* kr = &kq[(kbase + kt * 16 + l15) * DIM + quad * 8];
      kf[kt][0] = *(const s8v*)kr;
      kf[kt][1] = *(const s8v*)(kr + 32);
    }

    const short* vb = vsh[t & 1];
#pragma unroll
    for (int kp = 0; kp < 2; ++kp) {   // pair of 16-key sub-tiles
      i4v pai[2];                      // exp'd P, A-operand bits, per qt
#pragma unroll
      for (int h = 0; h < 2; ++h) {
        int kt = kp * 2 + h;
#pragma unroll
        for (int qt = 0; qt < 2; ++qt) {
          f4v acc = (f4v){0.f, 0.f, 0.f, 0.f};
          acc = __builtin_amdgcn_mfma_f32_16x16x32_bf16(kf[kt][0], qf[qt][0], acc, 0, 0, 0);
          acc = __builtin_amdgcn_mfma_f32_16x16x32_bf16(kf[kt][1], qf[qt][1], acc, 0, 0, 0);
          // acc[r] = S^T[key=kt*16+quad*4+r][query=qt*16+l15]
          float p0 = exp2f(acc[0] * SC2), p1 = exp2f(acc[1] * SC2);
          float p2 = exp2f(acc[2] * SC2), p3 = exp2f(acc[3] * SC2);
          ls[qt] += (p0 + p1) + (p2 + p3);
          pai[qt][h * 2]     = pack_bf16x2(p0, p1);
          pai[qt][h * 2 + 1] = pack_bf16x2(p2, p3);
        }
      }
#pragma unroll
      for (int c = 0; c < 4; ++c) {
        // B[n=dim=l15][k=quad*8+j], key = kp*32 + quad*4+(j&3)+16*(j>>2)
        const short* vr = &vb[(c * 16 + l15) * VSTR + kp * 32 + quad * 4];
        s4v v0 = *(const s4v*)vr;
        s4v v1 = *(const s4v*)(vr + 16);
        s8v vf = __builtin_shufflevector(v0, v1, 0, 1, 2, 3, 4, 5, 6, 7);
#pragma unroll
        for (int qt = 0; qt < 2; ++qt)
          o[qt][c] = __builtin_amdgcn_mfma_f32_16x16x32_bf16(
              __builtin_bit_cast(s8v, pai[qt]), vf, o[qt][c], 0, 0, 0);
      }
    }
  }

  // finish per-query row sums across quads (lane bits 4,5)
#pragma unroll
  for (int qt = 0; qt < 2; ++qt) {
    float v = ls[qt];
    v += __shfl_xor(v, 16);
    v += __shfl_xor(v, 32);
    ls[qt] = v;
  }

  // store bf16 partials + row sums
#pragma unroll
  for (int qt = 0; qt < 2; ++qt) {
#pragma unroll
    for (int r = 0; r < 4; ++r) {
      int q = qbase + qt * 16 + quad * 4 + r;
      size_t ob = ((size_t)split * NQ + q) * DIM;
#pragma unroll
      for (int c = 0; c < 4; ++c)
        pO[ob + c * 16 + l15] = f2b(o[qt][c][r]);
    }
    if (quad == 0) pL[split * NQ + qbase + qt * 16 + l15] = f2b(ls[qt]);
  }
}

// ---------------- merge partials + output projection (fp32 out) -------------
__global__ __launch_bounds__(256) void merge_kernel(
    const short* __restrict__ pO, const short* __restrict__ pL,
    const float* __restrict__ wo, const float* __restrict__ bo,
    float* __restrict__ out) {
  __shared__ __align__(16) short wsh[DIM * KSTR];
  __shared__ __align__(16) float att[MROWS * DIM];
  int tid = threadIdx.x;
  int q0 = blockIdx.x * MROWS;
  for (int i = tid; i < DIM * 16; i += 256) {
    int r = i >> 4, c4 = (i & 15) << 2;
    float4 w = *(const float4*)&wo[r * DIM + c4];
    s4v p = {f2b(w.x), f2b(w.y), f2b(w.z), f2b(w.w)};
    *(s4v*)&wsh[r * KSTR + c4] = p;
  }
  int e = tid & 63, rg = tid >> 6;
  for (int rr = rg; rr < MROWS; rr += 4) {
    int q = q0 + rr;
    float s = 0.f, l = 0.f;
#pragma unroll
    for (int sp = 0; sp < SPLITS; ++sp) {
      s += b2f(pO[((size_t)sp * NQ + q) * DIM + e]);
      l += b2f(pL[sp * NQ + q]);
    }
    att[rr * DIM + e] = s / l;
  }
  __syncthreads();
  for (int rr = rg; rr < MROWS; rr += 4) {
    float acc = bo[e];
#pragma unroll
    for (int c8 = 0; c8 < 8; ++c8) {
      s8v w = *(const s8v*)&wsh[e * KSTR + c8 * 8];
      const float* ar = &att[rr * DIM + c8 * 8];
      acc += ar[0] * b2f(w[0]) + ar[1] * b2f(w[1]) + ar[2] * b2f(w[2]) + ar[3] * b2f(w[3])
           + ar[4] * b2f(w[4]) + ar[5] * b2f(w[5]) + ar[6] * b2f(w[6]) + ar[7] * b2f(w[7]);
    }
    out[(size_t)(q0 + rr) * DIM + e] = acc;
  }
}

extern "C" void kernel_launch(void* const* d_in, const int* in_sizes, int n_in,
                              void* d_out, int out_size, void* d_ws, size_t ws_size,
                              hipStream_t stream) {
  const float* x  = (const float*)d_in[0];
  const float* wq = (const float*)d_in[1];
  const float* bq = (const float*)d_in[2];
  const float* wk = (const float*)d_in[3];
  const float* bk = (const float*)d_in[4];
  const float* wv = (const float*)d_in[5];
  const float* bv = (const float*)d_in[6];
  const float* th = (const float*)d_in[7];
  const float* wo = (const float*)d_in[8];
  const float* bo = (const float*)d_in[9];

  char* ws = (char*)d_ws;
  short* qq = (short*)(ws);                             // 1 MB
  short* kq = (short*)(ws + (1u << 20));                // 1 MB
  short* vq = (short*)(ws + (2u << 20));                // 1 MB
  short* pO = (short*)(ws + (3u << 20));                // 16 MB bf16 partials
  short* pL = (short*)(ws + (19u << 20));               // 256 KB bf16 row sums

  hipLaunchKernelGGL(qkv_kernel, dim3(NQ / QROWS), dim3(256), 0, stream,
                     x, wq, bq, wk, bk, wv, bv, th, qq, kq, vq);
  hipLaunchKernelGGL(flash_kernel, dim3(GRID_FLASH), dim3(256), 0, stream,
                     qq, kq, vq, pO, pL);
  hipLaunchKernelGGL(merge_kernel, dim3(MERGEB), dim3(256), 0, stream,
                     pO, pL, wo, bo, (float*)d_out);
}